// Round 11
// baseline (374.745 us; speedup 1.0000x reference)
//
#include <hip/hip_runtime.h>

#define H 32
#define GPB 8   // 32-lane groups per 256-thread block

// tanh(x) = 1 - 2/(1 + exp2(x * 2*log2(e))); saturates correctly at +/-inf.
__device__ __forceinline__ float fast_tanh(float x) {
    float e = __builtin_amdgcn_exp2f(x * 2.8853900817779268f);
    float r = __builtin_amdgcn_rcpf(e + 1.0f);
    return fmaf(-2.0f, r, 1.0f);
}

#define SWZ_X16 0x401F  // ds_swizzle BitMode: lane ^ 16 (per 32-lane group)

// x-projection: 5 FMAs off broadcast-loaded onehot/reward.
#define XP(oh, rwc) fmaf((oh).x, wih0, fmaf((oh).y, wih1, fmaf((oh).z, wih2, \
                     fmaf((oh).w, wih3, fmaf((rwc), wih4, bias)))))

// Readout chain ops: fused broadcast-FMA off an old (>=4-instr) source.
#define ROMUL(prv, src, w) \
    asm("s_nop 1\n\t" \
        "v_mul_f32_dpp %0, %1, %2 quad_perm:[0,0,0,0] row_mask:0xf bank_mask:0xf" \
        : "=&v"(prv) : "v"(src), "v"(w))
#define ROFMA(prv, src, w, q) \
    asm("v_fmac_f32_dpp %0, %1, %2 quad_perm:[" #q "," #q "," #q "," #q "] row_mask:0xf bank_mask:0xf" \
        : "+v"(prv) : "v"(src), "v"(w))
// dst = src + (src shifted down SH lanes); consumed only from lanes 12..15.
#define SHRADD(dst, src, SH) \
    asm("s_nop 1\n\t" \
        "v_mov_b32_dpp %0, %1 " SH " row_mask:0xf bank_mask:0xf\n\t" \
        "v_add_f32 %0, %1, %0" \
        : "=&v"(dst) : "v"(src))

// 16-half mat-vec: 16 fused v_fmac_f32_dpp + 3 row_ror:4, fixed schedule,
// every DPP source >= 4 instrs old => no wait-state hazards. Weights arrive
// as 16 NAMED scalar operands (register-resident by construction).
#define MV_HALF_FIRST(h, V0,V1,V2,V3,V4,V5,V6,V7,V8,V9,V10,V11,V12,V13,V14,V15) \
    asm("s_nop 1\n\t" \
        "v_mov_b32_dpp %4, %7 row_ror:4 row_mask:0xf bank_mask:0xf\n\t" \
        "v_fmac_f32_dpp %0, %7, %8 quad_perm:[0,0,0,0] row_mask:0xf bank_mask:0xf\n\t" \
        "v_mul_f32_dpp %1, %7, %9 quad_perm:[1,1,1,1] row_mask:0xf bank_mask:0xf\n\t" \
        "v_mul_f32_dpp %2, %7, %10 quad_perm:[2,2,2,2] row_mask:0xf bank_mask:0xf\n\t" \
        "v_mul_f32_dpp %3, %7, %11 quad_perm:[3,3,3,3] row_mask:0xf bank_mask:0xf\n\t" \
        "v_mov_b32_dpp %5, %4 row_ror:4 row_mask:0xf bank_mask:0xf\n\t" \
        "v_fmac_f32_dpp %0, %4, %12 quad_perm:[0,0,0,0] row_mask:0xf bank_mask:0xf\n\t" \
        "v_fmac_f32_dpp %1, %4, %13 quad_perm:[1,1,1,1] row_mask:0xf bank_mask:0xf\n\t" \
        "v_fmac_f32_dpp %2, %4, %14 quad_perm:[2,2,2,2] row_mask:0xf bank_mask:0xf\n\t" \
        "v_fmac_f32_dpp %3, %4, %15 quad_perm:[3,3,3,3] row_mask:0xf bank_mask:0xf\n\t" \
        "v_mov_b32_dpp %6, %5 row_ror:4 row_mask:0xf bank_mask:0xf\n\t" \
        "v_fmac_f32_dpp %0, %5, %16 quad_perm:[0,0,0,0] row_mask:0xf bank_mask:0xf\n\t" \
        "v_fmac_f32_dpp %1, %5, %17 quad_perm:[1,1,1,1] row_mask:0xf bank_mask:0xf\n\t" \
        "v_fmac_f32_dpp %2, %5, %18 quad_perm:[2,2,2,2] row_mask:0xf bank_mask:0xf\n\t" \
        "v_fmac_f32_dpp %3, %5, %19 quad_perm:[3,3,3,3] row_mask:0xf bank_mask:0xf\n\t" \
        "v_fmac_f32_dpp %0, %6, %20 quad_perm:[0,0,0,0] row_mask:0xf bank_mask:0xf\n\t" \
        "v_fmac_f32_dpp %1, %6, %21 quad_perm:[1,1,1,1] row_mask:0xf bank_mask:0xf\n\t" \
        "v_fmac_f32_dpp %2, %6, %22 quad_perm:[2,2,2,2] row_mask:0xf bank_mask:0xf\n\t" \
        "v_fmac_f32_dpp %3, %6, %23 quad_perm:[3,3,3,3] row_mask:0xf bank_mask:0xf" \
        : "+v"(a0), "=&v"(a1), "=&v"(a2), "=&v"(a3), \
          "=&v"(r1), "=&v"(r2), "=&v"(r3) \
        : "v"(h), "v"(V0), "v"(V1), "v"(V2), "v"(V3), \
          "v"(V4), "v"(V5), "v"(V6), "v"(V7), \
          "v"(V8), "v"(V9), "v"(V10), "v"(V11), \
          "v"(V12), "v"(V13), "v"(V14), "v"(V15))

#define MV_HALF_SECOND(h, V0,V1,V2,V3,V4,V5,V6,V7,V8,V9,V10,V11,V12,V13,V14,V15) \
    asm("v_mov_b32_dpp %4, %7 row_ror:4 row_mask:0xf bank_mask:0xf\n\t" \
        "v_fmac_f32_dpp %0, %7, %8 quad_perm:[0,0,0,0] row_mask:0xf bank_mask:0xf\n\t" \
        "v_fmac_f32_dpp %1, %7, %9 quad_perm:[1,1,1,1] row_mask:0xf bank_mask:0xf\n\t" \
        "v_fmac_f32_dpp %2, %7, %10 quad_perm:[2,2,2,2] row_mask:0xf bank_mask:0xf\n\t" \
        "v_fmac_f32_dpp %3, %7, %11 quad_perm:[3,3,3,3] row_mask:0xf bank_mask:0xf\n\t" \
        "v_mov_b32_dpp %5, %4 row_ror:4 row_mask:0xf bank_mask:0xf\n\t" \
        "v_fmac_f32_dpp %0, %4, %12 quad_perm:[0,0,0,0] row_mask:0xf bank_mask:0xf\n\t" \
        "v_fmac_f32_dpp %1, %4, %13 quad_perm:[1,1,1,1] row_mask:0xf bank_mask:0xf\n\t" \
        "v_fmac_f32_dpp %2, %4, %14 quad_perm:[2,2,2,2] row_mask:0xf bank_mask:0xf\n\t" \
        "v_fmac_f32_dpp %3, %4, %15 quad_perm:[3,3,3,3] row_mask:0xf bank_mask:0xf\n\t" \
        "v_mov_b32_dpp %6, %5 row_ror:4 row_mask:0xf bank_mask:0xf\n\t" \
        "v_fmac_f32_dpp %0, %5, %16 quad_perm:[0,0,0,0] row_mask:0xf bank_mask:0xf\n\t" \
        "v_fmac_f32_dpp %1, %5, %17 quad_perm:[1,1,1,1] row_mask:0xf bank_mask:0xf\n\t" \
        "v_fmac_f32_dpp %2, %5, %18 quad_perm:[2,2,2,2] row_mask:0xf bank_mask:0xf\n\t" \
        "v_fmac_f32_dpp %3, %5, %19 quad_perm:[3,3,3,3] row_mask:0xf bank_mask:0xf\n\t" \
        "v_fmac_f32_dpp %0, %6, %20 quad_perm:[0,0,0,0] row_mask:0xf bank_mask:0xf\n\t" \
        "v_fmac_f32_dpp %1, %6, %21 quad_perm:[1,1,1,1] row_mask:0xf bank_mask:0xf\n\t" \
        "v_fmac_f32_dpp %2, %6, %22 quad_perm:[2,2,2,2] row_mask:0xf bank_mask:0xf\n\t" \
        "v_fmac_f32_dpp %3, %6, %23 quad_perm:[3,3,3,3] row_mask:0xf bank_mask:0xf" \
        : "+v"(a0), "+v"(a1), "+v"(a2), "+v"(a3), \
          "=&v"(r1), "=&v"(r2), "=&v"(r3) \
        : "v"(h), "v"(V0), "v"(V1), "v"(V2), "v"(V3), \
          "v"(V4), "v"(V5), "v"(V6), "v"(V7), \
          "v"(V8), "v"(V9), "v"(V10), "v"(V11), \
          "v"(V12), "v"(V13), "v"(V14), "v"(V15))

// R9 post-mortem: VGPR_Count=56 < live set (~90) with zero scratch => the
// compiler was RE-LOADING weights/inputs from L1/L2 every step; that cache
// latency on the critical path is the persistent ~250-340 cyc stall seen in
// every round. This version shrinks the live set (named scalar weights, one
// input ring + precomputed xp) so everything is register-resident.
__global__ __launch_bounds__(256, 1) void rnn_fused(
    const float* __restrict__ onehot,   // [B,T,4]
    const float* __restrict__ rewards,  // [B,T]
    const float* __restrict__ W_ih,     // [H,5]
    const float* __restrict__ W_hh,     // [H,H]
    const float* __restrict__ b_ih,     // [H]
    const float* __restrict__ b_hh,     // [H]
    const float* __restrict__ W_ro,     // [4,H]
    const float* __restrict__ b_ro,     // [4]
    float* __restrict__ out_logits,     // [B,T,4]
    float* __restrict__ out_hT,         // [B,H]
    int T)
{
    const int tid = threadIdx.x;
    const int u   = tid & 31;            // hidden unit owned by this lane
    const int b   = blockIdx.x * GPB + (tid >> 5);
    const bool wr = (u >= 12) && (u < 16);  // lanes 12..15 store logits 0..3

    // ---- pre-permuted W_hh as 32 NAMED scalars. At stage s (after s
    // row_ror:4), quad-broadcast q delivers
    //   h[(u&16) + ((4*((u>>2)&3) + q - 4*s) & 15)]  (own half; ^16 other)
    const int base = u & 16;
    const int rb   = 4 * ((u >> 2) & 3);
    auto WP = [&](int half, int j) {
        const int s = j >> 2, bq = j & 3;
        const int kin = (rb + bq - 4 * s) & 15;
        return W_hh[u * H + (half ? (base ^ 16) : base) + kin];
    };
    const float w00=WP(0,0),  w01=WP(0,1),  w02=WP(0,2),  w03=WP(0,3),
                w04=WP(0,4),  w05=WP(0,5),  w06=WP(0,6),  w07=WP(0,7),
                w08=WP(0,8),  w09=WP(0,9),  w10=WP(0,10), w11=WP(0,11),
                w12=WP(0,12), w13=WP(0,13), w14=WP(0,14), w15=WP(0,15);
    const float x00=WP(1,0),  x01=WP(1,1),  x02=WP(1,2),  x03=WP(1,3),
                x04=WP(1,4),  x05=WP(1,5),  x06=WP(1,6),  x07=WP(1,7),
                x08=WP(1,8),  x09=WP(1,9),  x10=WP(1,10), x11=WP(1,11),
                x12=WP(1,12), x13=WP(1,13), x14=WP(1,14), x15=WP(1,15);

    const float wih0 = W_ih[u*5+0], wih1 = W_ih[u*5+1], wih2 = W_ih[u*5+2],
                wih3 = W_ih[u*5+3], wih4 = W_ih[u*5+4];
    const float bias = b_ih[u] + b_hh[u];
    // readout: lane u covers row r=u&3, columns = its quad and the twin quad.
    const float4 wroq  = *(const float4*)(W_ro + (u & 3) * H + (u & ~3));
    const float4 wroq2 = *(const float4*)(W_ro + (u & 3) * H + ((u & ~3) ^ 16));
    const float broz = b_ro[u & 3];

    const float* oh_ptr = onehot  + (size_t)b * T * 4;
    const float* rw_ptr = rewards + (size_t)b * T;
    float*       lg_ptr = out_logits + (size_t)b * T * 4;

    // ---- single 4-step input ring; xp extracted at block top so the ring
    //      carries no pressure through the steps ----
    float4 oh0, oh1, oh2, oh3, rwv;
    auto loadRing = [&](int t) {
        oh0 = *(const float4*)(oh_ptr + (size_t)t * 4);
        oh1 = *(const float4*)(oh_ptr + (size_t)(t + 1) * 4);
        oh2 = *(const float4*)(oh_ptr + (size_t)(t + 2) * 4);
        oh3 = *(const float4*)(oh_ptr + (size_t)(t + 3) * 4);
        rwv = *(const float4*)(rw_ptr + t);
    };

    float hj;  // running hidden state h^{t}

    // One step: consumes hj = h^{t-1} and precomputed xp_t, produces h^{t};
    // emits logits_{t-1}. Summation order identical to R9 (bit-exact).
    auto step = [&](float xp, int emit_t) {
        const float h0 = hj;
        const int hsb = __builtin_amdgcn_ds_swizzle(__float_as_int(h0), SWZ_X16);
        float a0 = xp, a1, a2, a3;
        float r1, r2, r3;
        MV_HALF_FIRST(h0, w00,w01,w02,w03,w04,w05,w06,w07,
                          w08,w09,w10,w11,w12,w13,w14,w15);   // own 16-half
        float pr;
        ROMUL(pr, h0, wroq.x);               // readout partials (own quads)
        ROFMA(pr, h0, wroq.y, 1);
        ROFMA(pr, h0, wroq.z, 2);
        ROFMA(pr, h0, wroq.w, 3);
        const float hs = __int_as_float(hsb);  // lgkmcnt-guarded at first use
        MV_HALF_SECOND(hs, x00,x01,x02,x03,x04,x05,x06,x07,
                           x08,x09,x10,x11,x12,x13,x14,x15);  // other 16-half
        ROFMA(pr, hs, wroq2.x, 0);
        ROFMA(pr, hs, wroq2.y, 1);
        ROFMA(pr, hs, wroq2.z, 2);
        ROFMA(pr, hs, wroq2.w, 3);
        float t1, t2;
        SHRADD(t1, pr, "row_shr:4");
        SHRADD(t2, t1, "row_shr:8");         // lanes 12..15 hold row sums
        if (wr) lg_ptr[(size_t)emit_t * 4 + (u & 3)] = t2 + broz;
        hj = fast_tanh((a0 + a1) + (a2 + a3));
    };

    // ---- prologue ----
    loadRing(0);
    float xp0 = XP(oh0, rwv.x), xp1 = XP(oh1, rwv.y),
          xp2 = XP(oh2, rwv.z), xp3 = XP(oh3, rwv.w);
    loadRing(4);                         // in flight during t = 0..3
    hj = fast_tanh(xp0);                 // t = 0 (h^{-1} = 0: mat-vec vanishes)
    step(xp1, 0);                        // t = 1, emits logits_0
    step(xp2, 1);
    step(xp3, 2);

    // ---- steady state: 4 steps / iteration; ring holds t = tb..tb+3 ----
    for (int tb = 4; tb < T; tb += 4) {
        xp0 = XP(oh0, rwv.x); xp1 = XP(oh1, rwv.y);
        xp2 = XP(oh2, rwv.z); xp3 = XP(oh3, rwv.w);
        if (tb + 4 < T) loadRing(tb + 4);   // hidden under the 4 steps below
        step(xp0, tb - 1);
        step(xp1, tb + 0);
        step(xp2, tb + 1);
        step(xp3, tb + 2);
    }

    // ---- tail: logits_{T-1} from h^{T-1} ----
    {
        const int hsb = __builtin_amdgcn_ds_swizzle(__float_as_int(hj), SWZ_X16);
        float pr;
        ROMUL(pr, hj, wroq.x);
        ROFMA(pr, hj, wroq.y, 1);
        ROFMA(pr, hj, wroq.z, 2);
        ROFMA(pr, hj, wroq.w, 3);
        const float hs = __int_as_float(hsb);
        ROFMA(pr, hs, wroq2.x, 0);
        ROFMA(pr, hs, wroq2.y, 1);
        ROFMA(pr, hs, wroq2.z, 2);
        ROFMA(pr, hs, wroq2.w, 3);
        float t1, t2;
        SHRADD(t1, pr, "row_shr:4");
        SHRADD(t2, t1, "row_shr:8");
        if (wr) lg_ptr[(size_t)(T - 1) * 4 + (u & 3)] = t2 + broz;
    }
    out_hT[(size_t)b * H + u] = hj;      // h_T
}

extern "C" void kernel_launch(void* const* d_in, const int* in_sizes, int n_in,
                              void* d_out, int out_size, void* d_ws, size_t ws_size,
                              hipStream_t stream) {
    const float* onehot  = (const float*)d_in[0];
    const float* rewards = (const float*)d_in[1];
    const float* W_ih    = (const float*)d_in[2];
    const float* W_hh    = (const float*)d_in[3];
    const float* b_ih    = (const float*)d_in[4];
    const float* b_hh    = (const float*)d_in[5];
    const float* W_ro    = (const float*)d_in[6];
    const float* b_ro    = (const float*)d_in[7];

    const int T = 1024;                  // per setup_inputs()
    const int B = in_sizes[1] / T;       // in_sizes[1] = B*T

    float* out_logits = (float*)d_out;                        // [B,T,4]
    float* out_hT     = (float*)d_out + (size_t)B * T * 4;    // [B,H]

    dim3 block(256);                     // 4 waves/block, 1024 waves total
    dim3 grid(B / GPB);                  // = 256 blocks -> 1 wave/SIMD chip-wide
    rnn_fused<<<grid, block, 0, stream>>>(onehot, rewards, W_ih, W_hh,
                                          b_ih, b_hh, W_ro, b_ro,
                                          out_logits, out_hT, T);
}

// Round 12
// 303.517 us; speedup vs baseline: 1.2347x; 1.2347x over previous
//
#include <hip/hip_runtime.h>

#define H 32
#define GPB 8   // 32-lane groups per 256-thread block

// tanh(x) = 1 - 2/(1 + exp2(x * 2*log2(e))); saturates correctly at +/-inf.
__device__ __forceinline__ float fast_tanh(float x) {
    float e = __builtin_amdgcn_exp2f(x * 2.8853900817779268f);
    float r = __builtin_amdgcn_rcpf(e + 1.0f);
    return fmaf(-2.0f, r, 1.0f);
}

#define SWZ_X16 0x401F  // ds_swizzle BitMode: lane ^ 16 (per 32-lane group)

// x-projection: 5 FMAs off broadcast-loaded onehot/reward.
#define XP(oh, rwc) fmaf((oh).x, wih0, fmaf((oh).y, wih1, fmaf((oh).z, wih2, \
                     fmaf((oh).w, wih3, fmaf((rwc), wih4, bias)))))

// Readout chain ops: fused broadcast-FMA off an old (>=4-instr) source.
#define ROMUL(prv, src, w) \
    asm("s_nop 1\n\t" \
        "v_mul_f32_dpp %0, %1, %2 quad_perm:[0,0,0,0] row_mask:0xf bank_mask:0xf" \
        : "=&v"(prv) : "v"(src), "v"(w))
#define ROFMA(prv, src, w, q) \
    asm("v_fmac_f32_dpp %0, %1, %2 quad_perm:[" #q "," #q "," #q "," #q "] row_mask:0xf bank_mask:0xf" \
        : "+v"(prv) : "v"(src), "v"(w))
// dst = src + (src shifted down SH lanes); consumed only from lanes 12..15.
#define SHRADD(dst, src, SH) \
    asm("s_nop 1\n\t" \
        "v_mov_b32_dpp %0, %1 " SH " row_mask:0xf bank_mask:0xf\n\t" \
        "v_add_f32 %0, %1, %0" \
        : "=&v"(dst) : "v"(src))

// 16-half mat-vec: 16 fused v_fmac_f32_dpp + 3 row_ror:4, fixed schedule,
// every DPP source >= 4 instrs old => no wait-state hazards.
#define MV_HALF_FIRST(h, V0,V1,V2,V3,V4,V5,V6,V7,V8,V9,V10,V11,V12,V13,V14,V15) \
    asm("s_nop 1\n\t" \
        "v_mov_b32_dpp %4, %7 row_ror:4 row_mask:0xf bank_mask:0xf\n\t" \
        "v_fmac_f32_dpp %0, %7, %8 quad_perm:[0,0,0,0] row_mask:0xf bank_mask:0xf\n\t" \
        "v_mul_f32_dpp %1, %7, %9 quad_perm:[1,1,1,1] row_mask:0xf bank_mask:0xf\n\t" \
        "v_mul_f32_dpp %2, %7, %10 quad_perm:[2,2,2,2] row_mask:0xf bank_mask:0xf\n\t" \
        "v_mul_f32_dpp %3, %7, %11 quad_perm:[3,3,3,3] row_mask:0xf bank_mask:0xf\n\t" \
        "v_mov_b32_dpp %5, %4 row_ror:4 row_mask:0xf bank_mask:0xf\n\t" \
        "v_fmac_f32_dpp %0, %4, %12 quad_perm:[0,0,0,0] row_mask:0xf bank_mask:0xf\n\t" \
        "v_fmac_f32_dpp %1, %4, %13 quad_perm:[1,1,1,1] row_mask:0xf bank_mask:0xf\n\t" \
        "v_fmac_f32_dpp %2, %4, %14 quad_perm:[2,2,2,2] row_mask:0xf bank_mask:0xf\n\t" \
        "v_fmac_f32_dpp %3, %4, %15 quad_perm:[3,3,3,3] row_mask:0xf bank_mask:0xf\n\t" \
        "v_mov_b32_dpp %6, %5 row_ror:4 row_mask:0xf bank_mask:0xf\n\t" \
        "v_fmac_f32_dpp %0, %5, %16 quad_perm:[0,0,0,0] row_mask:0xf bank_mask:0xf\n\t" \
        "v_fmac_f32_dpp %1, %5, %17 quad_perm:[1,1,1,1] row_mask:0xf bank_mask:0xf\n\t" \
        "v_fmac_f32_dpp %2, %5, %18 quad_perm:[2,2,2,2] row_mask:0xf bank_mask:0xf\n\t" \
        "v_fmac_f32_dpp %3, %5, %19 quad_perm:[3,3,3,3] row_mask:0xf bank_mask:0xf\n\t" \
        "v_fmac_f32_dpp %0, %6, %20 quad_perm:[0,0,0,0] row_mask:0xf bank_mask:0xf\n\t" \
        "v_fmac_f32_dpp %1, %6, %21 quad_perm:[1,1,1,1] row_mask:0xf bank_mask:0xf\n\t" \
        "v_fmac_f32_dpp %2, %6, %22 quad_perm:[2,2,2,2] row_mask:0xf bank_mask:0xf\n\t" \
        "v_fmac_f32_dpp %3, %6, %23 quad_perm:[3,3,3,3] row_mask:0xf bank_mask:0xf" \
        : "+v"(a0), "=&v"(a1), "=&v"(a2), "=&v"(a3), \
          "=&v"(r1), "=&v"(r2), "=&v"(r3) \
        : "v"(h), "v"(V0), "v"(V1), "v"(V2), "v"(V3), \
          "v"(V4), "v"(V5), "v"(V6), "v"(V7), \
          "v"(V8), "v"(V9), "v"(V10), "v"(V11), \
          "v"(V12), "v"(V13), "v"(V14), "v"(V15))

#define MV_HALF_SECOND(h, V0,V1,V2,V3,V4,V5,V6,V7,V8,V9,V10,V11,V12,V13,V14,V15) \
    asm("v_mov_b32_dpp %4, %7 row_ror:4 row_mask:0xf bank_mask:0xf\n\t" \
        "v_fmac_f32_dpp %0, %7, %8 quad_perm:[0,0,0,0] row_mask:0xf bank_mask:0xf\n\t" \
        "v_fmac_f32_dpp %1, %7, %9 quad_perm:[1,1,1,1] row_mask:0xf bank_mask:0xf\n\t" \
        "v_fmac_f32_dpp %2, %7, %10 quad_perm:[2,2,2,2] row_mask:0xf bank_mask:0xf\n\t" \
        "v_fmac_f32_dpp %3, %7, %11 quad_perm:[3,3,3,3] row_mask:0xf bank_mask:0xf\n\t" \
        "v_mov_b32_dpp %5, %4 row_ror:4 row_mask:0xf bank_mask:0xf\n\t" \
        "v_fmac_f32_dpp %0, %4, %12 quad_perm:[0,0,0,0] row_mask:0xf bank_mask:0xf\n\t" \
        "v_fmac_f32_dpp %1, %4, %13 quad_perm:[1,1,1,1] row_mask:0xf bank_mask:0xf\n\t" \
        "v_fmac_f32_dpp %2, %4, %14 quad_perm:[2,2,2,2] row_mask:0xf bank_mask:0xf\n\t" \
        "v_fmac_f32_dpp %3, %4, %15 quad_perm:[3,3,3,3] row_mask:0xf bank_mask:0xf\n\t" \
        "v_mov_b32_dpp %6, %5 row_ror:4 row_mask:0xf bank_mask:0xf\n\t" \
        "v_fmac_f32_dpp %0, %5, %16 quad_perm:[0,0,0,0] row_mask:0xf bank_mask:0xf\n\t" \
        "v_fmac_f32_dpp %1, %5, %17 quad_perm:[1,1,1,1] row_mask:0xf bank_mask:0xf\n\t" \
        "v_fmac_f32_dpp %2, %5, %18 quad_perm:[2,2,2,2] row_mask:0xf bank_mask:0xf\n\t" \
        "v_fmac_f32_dpp %3, %5, %19 quad_perm:[3,3,3,3] row_mask:0xf bank_mask:0xf\n\t" \
        "v_fmac_f32_dpp %0, %6, %20 quad_perm:[0,0,0,0] row_mask:0xf bank_mask:0xf\n\t" \
        "v_fmac_f32_dpp %1, %6, %21 quad_perm:[1,1,1,1] row_mask:0xf bank_mask:0xf\n\t" \
        "v_fmac_f32_dpp %2, %6, %22 quad_perm:[2,2,2,2] row_mask:0xf bank_mask:0xf\n\t" \
        "v_fmac_f32_dpp %3, %6, %23 quad_perm:[3,3,3,3] row_mask:0xf bank_mask:0xf" \
        : "+v"(a0), "+v"(a1), "+v"(a2), "+v"(a3), \
          "=&v"(r1), "=&v"(r2), "=&v"(r3) \
        : "v"(h), "v"(V0), "v"(V1), "v"(V2), "v"(V3), \
          "v"(V4), "v"(V5), "v"(V6), "v"(V7), \
          "v"(V8), "v"(V9), "v"(V10), "v"(V11), \
          "v"(V12), "v"(V13), "v"(V14), "v"(V15))

// R11 post-mortem: VGPR_Count stuck at 56 despite a ~100-value live set and
// zero scratch => LLVM REMATERIALIZES the weight loads inside the loop
// (invariant loads are "free" to its heuristic), putting ~41 L1 round trips
// (~200 cyc) on the recurrence chain every step. Fix: launder every
// persistent value through an empty asm — an asm def cannot be remat'd, so
// the allocator must keep them register-resident. Also batch logit stores
// 4-per-flush so store vmcnt waits amortize off the chain.
__global__ __launch_bounds__(256, 1) void rnn_fused(
    const float* __restrict__ onehot,   // [B,T,4]
    const float* __restrict__ rewards,  // [B,T]
    const float* __restrict__ W_ih,     // [H,5]
    const float* __restrict__ W_hh,     // [H,H]
    const float* __restrict__ b_ih,     // [H]
    const float* __restrict__ b_hh,     // [H]
    const float* __restrict__ W_ro,     // [4,H]
    const float* __restrict__ b_ro,     // [4]
    float* __restrict__ out_logits,     // [B,T,4]
    float* __restrict__ out_hT,         // [B,H]
    int T)
{
    const int tid = threadIdx.x;
    const int u   = tid & 31;            // hidden unit owned by this lane
    const int b   = blockIdx.x * GPB + (tid >> 5);
    const bool wr = (u >= 12) && (u < 16);  // lanes 12..15 store logits 0..3

    // ---- pre-permuted W_hh. At stage s (after s row_ror:4), quad-broadcast
    // q delivers h[(u&16) + ((4*((u>>2)&3) + q - 4*s) & 15)] (own; ^16 other)
    const int base = u & 16;
    const int rb   = 4 * ((u >> 2) & 3);
    auto WP = [&](int half, int j) {
        const int s = j >> 2, bq = j & 3;
        const int kin = (rb + bq - 4 * s) & 15;
        return W_hh[u * H + (half ? (base ^ 16) : base) + kin];
    };
    float w00=WP(0,0),  w01=WP(0,1),  w02=WP(0,2),  w03=WP(0,3),
          w04=WP(0,4),  w05=WP(0,5),  w06=WP(0,6),  w07=WP(0,7),
          w08=WP(0,8),  w09=WP(0,9),  w10=WP(0,10), w11=WP(0,11),
          w12=WP(0,12), w13=WP(0,13), w14=WP(0,14), w15=WP(0,15);
    float x00=WP(1,0),  x01=WP(1,1),  x02=WP(1,2),  x03=WP(1,3),
          x04=WP(1,4),  x05=WP(1,5),  x06=WP(1,6),  x07=WP(1,7),
          x08=WP(1,8),  x09=WP(1,9),  x10=WP(1,10), x11=WP(1,11),
          x12=WP(1,12), x13=WP(1,13), x14=WP(1,14), x15=WP(1,15);

    float wih0 = W_ih[u*5+0], wih1 = W_ih[u*5+1], wih2 = W_ih[u*5+2],
          wih3 = W_ih[u*5+3], wih4 = W_ih[u*5+4];
    float bias = b_ih[u] + b_hh[u];
    const float4 wroq  = *(const float4*)(W_ro + (u & 3) * H + (u & ~3));
    const float4 wroq2 = *(const float4*)(W_ro + (u & 3) * H + ((u & ~3) ^ 16));
    float wr0 = wroq.x,  wr1 = wroq.y,  wr2 = wroq.z,  wr3 = wroq.w;
    float wr4v = wroq2.x, wr5 = wroq2.y, wr6 = wroq2.z, wr7 = wroq2.w;
    float broz = b_ro[u & 3];

    // ---- anti-remat laundering: asm defs can't be rematerialized ----
    asm("" : "+v"(w00), "+v"(w01), "+v"(w02), "+v"(w03),
             "+v"(w04), "+v"(w05), "+v"(w06), "+v"(w07),
             "+v"(w08), "+v"(w09), "+v"(w10), "+v"(w11),
             "+v"(w12), "+v"(w13), "+v"(w14), "+v"(w15));
    asm("" : "+v"(x00), "+v"(x01), "+v"(x02), "+v"(x03),
             "+v"(x04), "+v"(x05), "+v"(x06), "+v"(x07),
             "+v"(x08), "+v"(x09), "+v"(x10), "+v"(x11),
             "+v"(x12), "+v"(x13), "+v"(x14), "+v"(x15));
    asm("" : "+v"(wr0), "+v"(wr1), "+v"(wr2), "+v"(wr3),
             "+v"(wr4v), "+v"(wr5), "+v"(wr6), "+v"(wr7),
             "+v"(broz), "+v"(wih0), "+v"(wih1), "+v"(wih2),
             "+v"(wih3), "+v"(wih4), "+v"(bias));

    const float* oh_ptr = onehot  + (size_t)b * T * 4;
    const float* rw_ptr = rewards + (size_t)b * T;
    float*       lg_ptr = out_logits + (size_t)b * T * 4;

    // ---- single 4-step input ring; xp extracted at block top ----
    float4 oh0, oh1, oh2, oh3, rwv;
    auto loadRing = [&](int t) {
        oh0 = *(const float4*)(oh_ptr + (size_t)t * 4);
        oh1 = *(const float4*)(oh_ptr + (size_t)(t + 1) * 4);
        oh2 = *(const float4*)(oh_ptr + (size_t)(t + 2) * 4);
        oh3 = *(const float4*)(oh_ptr + (size_t)(t + 3) * 4);
        rwv = *(const float4*)(rw_ptr + t);
    };

    float hj;  // running hidden state h^{t}

    // One step: consumes hj = h^{t-1} and xp_t, produces h^{t}; the logit of
    // h^{t-1} goes to a REGISTER (stored in a batched flush, off the chain).
    auto step = [&](float xp, float& lgout) {
        const float h0 = hj;
        const int hsb = __builtin_amdgcn_ds_swizzle(__float_as_int(h0), SWZ_X16);
        float a0 = xp, a1, a2, a3;
        float r1, r2, r3;
        MV_HALF_FIRST(h0, w00,w01,w02,w03,w04,w05,w06,w07,
                          w08,w09,w10,w11,w12,w13,w14,w15);   // own 16-half
        float pr;
        ROMUL(pr, h0, wr0);                  // readout partials (own quads)
        ROFMA(pr, h0, wr1, 1);
        ROFMA(pr, h0, wr2, 2);
        ROFMA(pr, h0, wr3, 3);
        const float hs = __int_as_float(hsb);  // lgkmcnt-guarded at first use
        MV_HALF_SECOND(hs, x00,x01,x02,x03,x04,x05,x06,x07,
                           x08,x09,x10,x11,x12,x13,x14,x15);  // other 16-half
        ROFMA(pr, hs, wr4v, 0);
        ROFMA(pr, hs, wr5, 1);
        ROFMA(pr, hs, wr6, 2);
        ROFMA(pr, hs, wr7, 3);
        float t1, t2;
        SHRADD(t1, pr, "row_shr:4");
        SHRADD(t2, t1, "row_shr:8");         // lanes 12..15 hold row sums
        lgout = t2 + broz;
        hj = fast_tanh((a0 + a1) + (a2 + a3));
    };

    float lg0, lg1, lg2, lg3;

    // ---- prologue ----
    loadRing(0);
    float xp0 = XP(oh0, rwv.x), xp1 = XP(oh1, rwv.y),
          xp2 = XP(oh2, rwv.z), xp3 = XP(oh3, rwv.w);
    loadRing(4);                         // in flight during t = 0..3
    hj = fast_tanh(xp0);                 // t = 0 (h^{-1} = 0: mat-vec vanishes)
    step(xp1, lg0);                      // t = 1, logit_0
    step(xp2, lg1);                      // t = 2, logit_1
    step(xp3, lg2);                      // t = 3, logit_2
    if (wr) {                            // flush prologue logits 0..2
        lg_ptr[(size_t)0 * 4 + (u & 3)] = lg0;
        lg_ptr[(size_t)1 * 4 + (u & 3)] = lg1;
        lg_ptr[(size_t)2 * 4 + (u & 3)] = lg2;
    }

    // ---- steady state: 4 steps / iteration; logits tb-1..tb+2 flushed once
    for (int tb = 4; tb < T; tb += 4) {
        xp0 = XP(oh0, rwv.x); xp1 = XP(oh1, rwv.y);
        xp2 = XP(oh2, rwv.z); xp3 = XP(oh3, rwv.w);
        if (tb + 4 < T) loadRing(tb + 4);   // hidden under the 4 steps below
        step(xp0, lg0);                  // t = tb,   logit_{tb-1}
        step(xp1, lg1);                  // t = tb+1, logit_{tb}
        step(xp2, lg2);                  // t = tb+2, logit_{tb+1}
        step(xp3, lg3);                  // t = tb+3, logit_{tb+2}
        if (wr) {
            float* p = lg_ptr + (size_t)(tb - 1) * 4 + (u & 3);
            p[0]  = lg0;
            p[4]  = lg1;
            p[8]  = lg2;
            p[12] = lg3;
        }
    }

    // ---- tail: logits_{T-1} from h^{T-1} ----
    {
        const int hsb = __builtin_amdgcn_ds_swizzle(__float_as_int(hj), SWZ_X16);
        float pr;
        ROMUL(pr, hj, wr0);
        ROFMA(pr, hj, wr1, 1);
        ROFMA(pr, hj, wr2, 2);
        ROFMA(pr, hj, wr3, 3);
        const float hs = __int_as_float(hsb);
        ROFMA(pr, hs, wr4v, 0);
        ROFMA(pr, hs, wr5, 1);
        ROFMA(pr, hs, wr6, 2);
        ROFMA(pr, hs, wr7, 3);
        float t1, t2;
        SHRADD(t1, pr, "row_shr:4");
        SHRADD(t2, t1, "row_shr:8");
        if (wr) lg_ptr[(size_t)(T - 1) * 4 + (u & 3)] = t2 + broz;
    }
    out_hT[(size_t)b * H + u] = hj;      // h_T
}

extern "C" void kernel_launch(void* const* d_in, const int* in_sizes, int n_in,
                              void* d_out, int out_size, void* d_ws, size_t ws_size,
                              hipStream_t stream) {
    const float* onehot  = (const float*)d_in[0];
    const float* rewards = (const float*)d_in[1];
    const float* W_ih    = (const float*)d_in[2];
    const float* W_hh    = (const float*)d_in[3];
    const float* b_ih    = (const float*)d_in[4];
    const float* b_hh    = (const float*)d_in[5];
    const float* W_ro    = (const float*)d_in[6];
    const float* b_ro    = (const float*)d_in[7];

    const int T = 1024;                  // per setup_inputs()
    const int B = in_sizes[1] / T;       // in_sizes[1] = B*T

    float* out_logits = (float*)d_out;                        // [B,T,4]
    float* out_hT     = (float*)d_out + (size_t)B * T * 4;    // [B,H]

    dim3 block(256);                     // 4 waves/block, 1024 waves total
    dim3 grid(B / GPB);                  // = 256 blocks -> 1 wave/SIMD chip-wide
    rnn_fused<<<grid, block, 0, stream>>>(onehot, rewards, W_ih, W_hh,
                                          b_ih, b_hh, W_ro, b_ro,
                                          out_logits, out_hT, T);
}